// Round 5
// baseline (25843.515 us; speedup 1.0000x reference)
//
#include <hip/hip_runtime.h>

#define Bn 64
#define Cn 128
#define Hn 36
#define Wn 100
#define KSn 9

#define B_STRIDE (Cn * Hn * Wn)  // 460800
#define C_STRIDE (Hn * Wn)       // 3600

// prepped weights:
//  H path: [coq(32)][ci(128)][WQ_CHUNK=40]  (4 co x 9 taps = 36 used)
//  W path: [cop(64)][ci(128)][WP_CHUNK=20]  (2 co x 9 taps = 18 used)
#define WQ_CHUNK 40
#define WP_CHUNK 20
#define WQ_SIZE (32 * Cn * WQ_CHUNK)  // 163840 floats
#define WP_SIZE (64 * Cn * WP_CHUNK)  // 163840 floats

// ---------------- copy x -> buf ----------------
__global__ void __launch_bounds__(256) k_copy(const float4* __restrict__ s,
                                              float4* __restrict__ d, int n4) {
  int i = blockIdx.x * 256 + threadIdx.x;
  if (i < n4) d[i] = s[i];
}

__global__ void __launch_bounds__(256) k_zero(unsigned* p, int n) {
  int i = blockIdx.x * 256 + threadIdx.x;
  if (i < n) p[i] = 0u;
}

// ---------------- weight prep ----------------
__global__ void __launch_bounds__(256) k_prep_q(const float* __restrict__ w,
                                                float* __restrict__ o) {
  int i = blockIdx.x * 256 + threadIdx.x;
  if (i >= 32 * Cn * 36) return;
  int k = i % 9, j = (i / 9) % 4, ci = (i / 36) % Cn, coq = i / (36 * Cn);
  o[(coq * Cn + ci) * WQ_CHUNK + j * 9 + k] = w[((coq * 4 + j) * Cn + ci) * KSn + k];
}
__global__ void __launch_bounds__(256) k_prep_p(const float* __restrict__ w,
                                                float* __restrict__ o) {
  int i = blockIdx.x * 256 + threadIdx.x;
  if (i >= 64 * Cn * 18) return;
  int k = i % 9, j = (i / 9) % 2, ci = (i / 18) % Cn, cop = i / (18 * Cn);
  o[(cop * Cn + ci) * WP_CHUNK + j * 9 + k] = w[((cop * 2 + j) * Cn + ci) * KSn + k];
}

// ---------------- per-b 4-block spin barrier (agent scope) — proven R3 ----
__device__ __forceinline__ void bbar(unsigned* c, unsigned target) {
  __syncthreads();
  if (threadIdx.x == 0) {
    __hip_atomic_fetch_add(c, 1u, __ATOMIC_RELEASE, __HIP_MEMORY_SCOPE_AGENT);
    while (__hip_atomic_load(c, __ATOMIC_RELAXED, __HIP_MEMORY_SCOPE_AGENT) <
           target)
      __builtin_amdgcn_s_sleep(1);
    __builtin_amdgcn_fence(__ATOMIC_ACQUIRE, "agent");
  }
  __syncthreads();
}

// ---------------- tap FMA block: all indices compile-time after unroll ----
template <int NCO>
__device__ __forceinline__ void fma_taps(const float4* q, const float* pp,
                                         float* acc) {
#pragma unroll
  for (int j = 0; j < NCO; ++j)
#pragma unroll
    for (int k = 0; k < KSn; ++k) {
      const int d = j * 9 + k;
      const float wv = ((d & 3) == 0)   ? q[d >> 2].x
                       : ((d & 3) == 1) ? q[d >> 2].y
                       : ((d & 3) == 2) ? q[d >> 2].z
                                        : q[d >> 2].w;
      acc[j] = fmaf(pp[k], wv, acc[j]);
    }
}

// ---------------- fused H kernel (down + up), persistent ----------------
// grid (64 b, 4 cg) = 256 blocks (1/CU guaranteed: 55.3 KB LDS, 1024 thr,
// VGPR<=128 via launch_bounds). 16 waves: wave v -> (quad = v>>1, whalf=v&1);
// lane<50 -> w = whalf*50+lane. Weights: VMEM (opaque vz) + 1-ci reg dbuf.
__global__ void __launch_bounds__(1024, 1) k_hfused3(float* __restrict__ buf,
                                                     const float* __restrict__ pwd,
                                                     const float* __restrict__ pwu,
                                                     unsigned* __restrict__ ctr) {
  __shared__ float prev[Cn][Wn + 8];  // 55.3 KB
  const int b = blockIdx.x, cg = blockIdx.y, t = threadIdx.x;
  const int lane = t & 63;
  const int v = __builtin_amdgcn_readfirstlane(t >> 6);
  const int quad = v >> 1, wh = v & 1;
  const int coqg = cg * 8 + quad;  // global co-quad 0..31
  const int w = wh * 50 + lane;
  int vz;
  asm volatile("v_mov_b32 %0, 0" : "=v"(vz));  // opaque 0 -> force VMEM weights
  unsigned* myc = ctr + b;
  unsigned gen = 0;

  for (int phase = 0; phase < 2; ++phase) {
    const float* wsel = phase ? pwu : pwd;
    const float* wb = wsel + (size_t)coqg * Cn * WQ_CHUNK + vz;
    for (int s = 0; s < Hn - 1; ++s) {
      const int hc = phase ? (Hn - 2 - s) : (1 + s);
      const int hp = phase ? (hc + 1) : (hc - 1);

      const float* rb = buf + ((size_t)b * Cn * Hn + hp) * Wn;
      for (int g = t; g < Cn * 25; g += 1024) {
        int ci = g / 25, wq = g % 25;
        *(float4*)&prev[ci][4 + wq * 4] =
            *(const float4*)(rb + (size_t)ci * C_STRIDE + wq * 4);
      }
      for (int g = t; g < Cn * 8; g += 1024) {
        int ci = g >> 3, sp = g & 7;
        prev[ci][(sp < 4) ? sp : (Wn + sp)] = 0.f;
      }
      __syncthreads();

      if (lane < 50) {
        float acc[4] = {0.f, 0.f, 0.f, 0.f};
        float4 qa[9], qb[9];
#pragma unroll
        for (int r = 0; r < 9; ++r) qa[r] = ((const float4*)wb)[r];
#pragma unroll 1
        for (int ci = 0; ci < Cn; ci += 2) {
          const float4* n1 = (const float4*)(wb + (ci + 1) * WQ_CHUNK);
#pragma unroll
          for (int r = 0; r < 9; ++r) qb[r] = n1[r];
          float pp[9];
#pragma unroll
          for (int k = 0; k < KSn; ++k) pp[k] = prev[ci][w + k];
          fma_taps<4>(qa, pp, acc);
          if (ci + 2 < Cn) {
            const float4* n2 = (const float4*)(wb + (ci + 2) * WQ_CHUNK);
#pragma unroll
            for (int r = 0; r < 9; ++r) qa[r] = n2[r];
          }
#pragma unroll
          for (int k = 0; k < KSn; ++k) pp[k] = prev[ci + 1][w + k];
          fma_taps<4>(qb, pp, acc);
        }
        float* ob = buf + ((size_t)(b * Cn + coqg * 4) * Hn + hc) * Wn + w;
#pragma unroll
        for (int j = 0; j < 4; ++j) ob[(size_t)j * C_STRIDE] += fmaxf(acc[j], 0.f);
      }
      ++gen;
      bbar(myc, gen * 4u);  // 4 blocks per b
    }
  }
}

// ---------------- fused W kernel (right + left), transposed [b][c][w][h] ----
// grid (64 b, 4 cg) = 256 blocks; 1024 thr = 16 waves; wave v -> co-pair
// cop = cg*16+v; lane<36 -> h. 22.5 KB LDS. VMEM weights + reg dbuf.
__global__ void __launch_bounds__(1024, 1) k_wfused3(float* __restrict__ tb,
                                                     const float* __restrict__ pwr,
                                                     const float* __restrict__ pwl,
                                                     unsigned* __restrict__ ctr) {
  __shared__ float prev[Cn][Hn + 8];  // 22.5 KB
  const int b = blockIdx.x, cg = blockIdx.y, t = threadIdx.x;
  const int lane = t & 63;
  const int v = __builtin_amdgcn_readfirstlane(t >> 6);
  const int cop = cg * 16 + v;  // global co-pair 0..63
  int vz;
  asm volatile("v_mov_b32 %0, 0" : "=v"(vz));
  unsigned* myc = ctr + b;
  unsigned gen = 0;

  for (int phase = 0; phase < 2; ++phase) {
    const float* wsel = phase ? pwl : pwr;
    const float* wb = wsel + (size_t)cop * Cn * WP_CHUNK + vz;
    for (int s = 0; s < Wn - 1; ++s) {
      const int wc = phase ? (Wn - 2 - s) : (1 + s);
      const int wpos = phase ? (wc + 1) : (wc - 1);

      const float* cb = tb + ((size_t)b * Cn * Wn + wpos) * Hn;
      for (int g = t; g < Cn * 9; g += 1024) {
        int ci = g / 9, hq = g % 9;
        *(float4*)&prev[ci][4 + hq * 4] =
            *(const float4*)(cb + (size_t)ci * C_STRIDE + hq * 4);
      }
      for (int g = t; g < Cn * 8; g += 1024) {
        int ci = g >> 3, sp = g & 7;
        prev[ci][(sp < 4) ? sp : (Hn + sp)] = 0.f;
      }
      __syncthreads();

      if (lane < Hn) {
        float acc[2] = {0.f, 0.f};
        float4 qa[5], qb[5];
#pragma unroll
        for (int r = 0; r < 5; ++r) qa[r] = ((const float4*)wb)[r];
#pragma unroll 1
        for (int ci = 0; ci < Cn; ci += 2) {
          const float4* n1 = (const float4*)(wb + (ci + 1) * WP_CHUNK);
#pragma unroll
          for (int r = 0; r < 5; ++r) qb[r] = n1[r];
          float pp[9];
#pragma unroll
          for (int k = 0; k < KSn; ++k) pp[k] = prev[ci][lane + k];
          fma_taps<2>(qa, pp, acc);
          if (ci + 2 < Cn) {
            const float4* n2 = (const float4*)(wb + (ci + 2) * WP_CHUNK);
#pragma unroll
            for (int r = 0; r < 5; ++r) qa[r] = n2[r];
          }
#pragma unroll
          for (int k = 0; k < KSn; ++k) pp[k] = prev[ci + 1][lane + k];
          fma_taps<2>(qb, pp, acc);
        }
        float* ob = tb + ((size_t)(b * Cn + cop * 2) * Wn + wc) * Hn + lane;
        ob[0] += fmaxf(acc[0], 0.f);
        ob[C_STRIDE] += fmaxf(acc[1], 0.f);
      }
      ++gen;
      bbar(myc, gen * 4u);  // 4 blocks per b
    }
  }
}

// ---------------- transposes ----------------
__global__ void __launch_bounds__(256) k_t_hw2wh(const float* __restrict__ in,
                                                 float* __restrict__ out) {
  __shared__ float tile[Hn][Wn + 1];
  const int bc = blockIdx.x;
  const float* ib = in + (size_t)bc * C_STRIDE;
  float* ob = out + (size_t)bc * C_STRIDE;
  for (int f = threadIdx.x; f < Hn * Wn; f += 256) tile[f / Wn][f % Wn] = ib[f];
  __syncthreads();
  for (int f = threadIdx.x; f < Hn * Wn; f += 256) {
    int w = f / Hn, hh = f % Hn;
    ob[f] = tile[hh][w];
  }
}
__global__ void __launch_bounds__(256) k_t_wh2hw(const float* __restrict__ in,
                                                 float* __restrict__ out) {
  __shared__ float tile[Hn][Wn + 1];
  const int bc = blockIdx.x;
  const float* ib = in + (size_t)bc * C_STRIDE;
  float* ob = out + (size_t)bc * C_STRIDE;
  for (int f = threadIdx.x; f < Hn * Wn; f += 256) {
    int w = f / Hn, hh = f % Hn;
    tile[hh][w] = ib[f];
  }
  __syncthreads();
  for (int f = threadIdx.x; f < Hn * Wn; f += 256) ob[f] = tile[f / Wn][f % Wn];
}

// ---------------- raw fallback kernels (no workspace) ----------------
__global__ void __launch_bounds__(128) k_hstep(float* __restrict__ buf,
                                               const float* __restrict__ wt,
                                               int hp, int hc) {
  __shared__ float prev[Cn][Wn + 8];
  const int b = blockIdx.x;
  const int cog = blockIdx.y;
  const int t = threadIdx.x;
  const float* rb = buf + ((size_t)b * Cn * Hn + hp) * Wn;
  for (int g = t; g < Cn * (Wn / 4); g += 128) {
    int ci = g / 25, wq = g % 25;
    float4 vv = *(const float4*)(rb + (size_t)ci * C_STRIDE + wq * 4);
    *(float4*)&prev[ci][4 + wq * 4] = vv;
  }
  for (int g = t; g < Cn * 8; g += 128) {
    int ci = g >> 3, sp = g & 7;
    prev[ci][(sp < 4) ? sp : (Wn + sp)] = 0.f;
  }
  __syncthreads();
  if (t >= Wn) return;
  float acc[8] = {0.f, 0.f, 0.f, 0.f, 0.f, 0.f, 0.f, 0.f};
  const float* wb = wt + (size_t)cog * 8 * Cn * KSn;
  for (int ci = 0; ci < Cn; ++ci) {
    float p[KSn];
#pragma unroll
    for (int k = 0; k < KSn; ++k) p[k] = prev[ci][t + k];
#pragma unroll
    for (int j = 0; j < 8; ++j) {
      const float* w9 = wb + ((size_t)j * Cn + ci) * KSn;
#pragma unroll
      for (int k = 0; k < KSn; ++k) acc[j] = fmaf(p[k], w9[k], acc[j]);
    }
  }
  float* ob = buf + ((size_t)(b * Cn + cog * 8) * Hn + hc) * Wn + t;
#pragma unroll
  for (int j = 0; j < 8; ++j) ob[(size_t)j * C_STRIDE] += fmaxf(acc[j], 0.f);
}
__global__ void __launch_bounds__(128) k_wstep_d(float* __restrict__ buf,
                                                 const float* __restrict__ wt,
                                                 int wpos, int wc) {
  __shared__ float prev[Cn][Hn + 8];
  const int b = blockIdx.x;
  const int cog = blockIdx.y;
  const int t = threadIdx.x;
  const int h = t & 63;
  const int jb = __builtin_amdgcn_readfirstlane((t >> 6) * 4);
  for (int g = t; g < Cn * Hn; g += 128) {
    int ci = g / Hn, hh = g % Hn;
    prev[ci][4 + hh] = buf[((size_t)(b * Cn + ci) * Hn + hh) * Wn + wpos];
  }
  for (int g = t; g < Cn * 8; g += 128) {
    int ci = g >> 3, sp = g & 7;
    prev[ci][(sp < 4) ? sp : (Hn + sp)] = 0.f;
  }
  __syncthreads();
  if (h >= Hn) return;
  float acc[4] = {0.f, 0.f, 0.f, 0.f};
  const float* wb = wt + (size_t)(cog * 8 + jb) * Cn * KSn;
  for (int ci = 0; ci < Cn; ++ci) {
    float p[KSn];
#pragma unroll
    for (int k = 0; k < KSn; ++k) p[k] = prev[ci][h + k];
#pragma unroll
    for (int j = 0; j < 4; ++j) {
      const float* w9 = wb + ((size_t)j * Cn + ci) * KSn;
#pragma unroll
      for (int k = 0; k < KSn; ++k) acc[j] = fmaf(p[k], w9[k], acc[j]);
    }
  }
  float* ob = buf + ((size_t)(b * Cn + cog * 8 + jb) * Hn + h) * Wn + wc;
#pragma unroll
  for (int j = 0; j < 4; ++j) ob[(size_t)j * C_STRIDE] += fmaxf(acc[j], 0.f);
}

extern "C" void kernel_launch(void* const* d_in, const int* in_sizes, int n_in,
                              void* d_out, int out_size, void* d_ws, size_t ws_size,
                              hipStream_t stream) {
  (void)in_sizes; (void)n_in; (void)out_size;
  const float* x  = (const float*)d_in[0];
  const float* wd = (const float*)d_in[1];
  const float* wu = (const float*)d_in[2];
  const float* wr = (const float*)d_in[3];
  const float* wl = (const float*)d_in[4];
  float* buf = (float*)d_out;
  const size_t nelem = (size_t)Bn * B_STRIDE;  // 29,491,200 floats
  const size_t need =
      (nelem + 2 * (size_t)WQ_SIZE + 2 * (size_t)WP_SIZE) * 4 + 512;

  k_copy<<<(int)(nelem / 4 + 255) / 256, 256, 0, stream>>>(
      (const float4*)x, (float4*)buf, (int)(nelem / 4));

  if (ws_size >= need) {
    float* tb  = (float*)d_ws;  // transposed buffer
    float* pwd = tb + nelem;    // prepped weights
    float* pwu = pwd + WQ_SIZE;
    float* pwr = pwu + WQ_SIZE;
    float* pwl = pwr + WP_SIZE;
    unsigned* ctr = (unsigned*)(pwl + WP_SIZE);  // 128 counters

    k_zero<<<1, 256, 0, stream>>>(ctr, 128);
    k_prep_q<<<(32 * Cn * 36 + 255) / 256, 256, 0, stream>>>(wd, pwd);
    k_prep_q<<<(32 * Cn * 36 + 255) / 256, 256, 0, stream>>>(wu, pwu);
    k_prep_p<<<(64 * Cn * 18 + 255) / 256, 256, 0, stream>>>(wr, pwr);
    k_prep_p<<<(64 * Cn * 18 + 255) / 256, 256, 0, stream>>>(wl, pwl);

    dim3 g4(Bn, 4);  // 256 blocks -> guaranteed co-resident (1/CU)
    k_hfused3<<<g4, 1024, 0, stream>>>(buf, pwd, pwu, ctr);
    k_t_hw2wh<<<Bn * Cn, 256, 0, stream>>>(buf, tb);
    k_wfused3<<<g4, 1024, 0, stream>>>(tb, pwr, pwl, ctr + 64);
    k_t_wh2hw<<<Bn * Cn, 256, 0, stream>>>(tb, buf);
  } else {
    // raw fallback (no workspace)
    dim3 g8(Bn, Cn / 8);
    for (int hh = 1; hh < Hn; ++hh)
      k_hstep<<<g8, 128, 0, stream>>>(buf, wd, hh - 1, hh);
    for (int hh = Hn - 2; hh >= 0; --hh)
      k_hstep<<<g8, 128, 0, stream>>>(buf, wu, hh + 1, hh);
    for (int ww = 1; ww < Wn; ++ww)
      k_wstep_d<<<g8, 128, 0, stream>>>(buf, wr, ww - 1, ww);
    for (int ww = Wn - 2; ww >= 0; --ww)
      k_wstep_d<<<g8, 128, 0, stream>>>(buf, wl, ww + 1, ww);
  }
}